// Round 1
// baseline (615.301 us; speedup 1.0000x reference)
//
#include <hip/hip_runtime.h>
#include <cfloat>

// Problem: B=2, M=8, I=128, J=64, DIM=512, HEADS=8, DH=64, INNER=512.
// R = B*M*I = 2048 independent "query rows"; each attends over its own 64
// memory slots (mems row block [64][512]).
//
// Algebraic refactor (J << DIM):
//   sim[r,h,j] = sum_e mems[r,j,e] * T[r,h,e],  T[r,h,e] = sum_d Q[r,h,d]*Wkv[e, h*64+d]
//   out        = (sum_j attn[r,h,j]*mems[r,j,:]) @ Wv_h  @ Wo + bo
// => avoids materializing K/V (saves 137 GFLOP + 512 MB); total ~6.4 GF fp32,
//    memory-bound on one 256 MB pass over mems.
//
// ws layout (fp32): Q[2048][512] | T[2048][4096] | cbar[2048][4096] | O[2048][512]
//   = 72 MB total.

#define SCALE 0.125f

// ---------------------------------------------------------------------------
// Generic skinny GEMM, "column-per-lane" style (no LDS):
//   C[r0+i][t] = alpha * sum_e A[r0+i][hoff+e] * B[e*ldb + bcol0 + t] (+ bias[t])
// A accesses are wave-uniform (blockIdx + loop + readfirstlane'd head) -> s_load;
// B rows are read coalesced across lanes (L2-resident weights).
// 8 rows/block amortize B traffic: 256 blocks * 1 MB = 256 MB L2 (~7.4 us).
// ---------------------------------------------------------------------------
__global__ __launch_bounds__(512) void k_clrb(
    const float* __restrict__ A, int lda, int a_hs,
    const float* __restrict__ B, int ldb, int bcol0,
    const float* __restrict__ bias, float alpha,
    float* __restrict__ C, int ldc, int K)
{
  const int t  = threadIdx.x;           // output column (0..511)
  const int r0 = blockIdx.x * 8;
  int hoff = 0;
  if (a_hs) hoff = __builtin_amdgcn_readfirstlane(t >> 6) * a_hs; // head = wave
  const float* a0 = A + (size_t)r0 * lda + hoff;
  const float* bp = B + bcol0 + t;
  float acc[8];
#pragma unroll
  for (int i = 0; i < 8; ++i) acc[i] = 0.f;
  for (int e = 0; e < K; e += 8) {
#pragma unroll
    for (int ee = 0; ee < 8; ++ee) {
      float bv = bp[(size_t)(e + ee) * ldb];          // coalesced across lanes
#pragma unroll
      for (int i = 0; i < 8; ++i)
        acc[i] += a0[(size_t)i * lda + e + ee] * bv;  // uniform -> s_load
    }
  }
  float bb = bias ? bias[t] : 0.f;
#pragma unroll
  for (int i = 0; i < 8; ++i)
    C[(size_t)(r0 + i) * ldc + t] = acc[i] * alpha + bb;
}

// ---------------------------------------------------------------------------
// T[r][h*512+e] = sum_d Q[r][h*64+d] * Wkv[e][h*64+d]   (per-head NT, K=64)
// B access is per-lane strided (lane e reads 64 consecutive floats of its own
// Wkv row) -- L1 absorbs the stride (4 KB working set per wave, Wkv L2-hot).
// ---------------------------------------------------------------------------
__global__ __launch_bounds__(512) void k_tmat(
    const float* __restrict__ Q, const float* __restrict__ Wkv,
    float* __restrict__ T)
{
  const int e  = threadIdx.x;
  const int r0 = blockIdx.x * 8;
  const int h  = blockIdx.y;
  const float* q0 = Q + (size_t)r0 * 512 + h * 64;     // uniform -> s_load
  const float* bp = Wkv + (size_t)e * 1024 + h * 64;
  float acc[8];
#pragma unroll
  for (int i = 0; i < 8; ++i) acc[i] = 0.f;
#pragma unroll
  for (int d = 0; d < 64; ++d) {
    float bv = bp[d];
#pragma unroll
    for (int i = 0; i < 8; ++i) acc[i] += q0[(size_t)i * 512 + d] * bv;
  }
  float* o = T + (size_t)r0 * 4096 + h * 512 + e;
#pragma unroll
  for (int i = 0; i < 8; ++i) o[(size_t)i * 4096] = acc[i];
}

// ---------------------------------------------------------------------------
// K2: per row r -- sim = mems_row @ T_row^T, mask, softmax(j), cbar = attn @ mems_row.
// 512 threads = 8 waves. Thread (j = t&63, cseg = t>>6) holds mems[r][j][cseg*64..+64)
// in 64 REGISTERS (sim never touches LDS for m; T comes in via wave-uniform
// scalar loads). cbar needs the transpose-ish access, so regs are spilled to a
// padded LDS tile [64][132] in 4 column phases (keeps static LDS at 51 KB ->
// 2 blocks/CU so staging of one block overlaps compute of the other).
// ---------------------------------------------------------------------------
__global__ __launch_bounds__(512, 4) void k_attn(
    const float* __restrict__ mems, const float* __restrict__ Tm,
    const int* __restrict__ mask, float* __restrict__ cbar)
{
  // [0,8448): m_q [64][132] (pad 4 -> bank stride 4, b128-aligned rows)
  // [8448,12544): part (sim partials [8 cseg][8 h][64 j]) / cbar partials [4][8][128]
  // [12544,13056): p_s [64 j][8 h]
  __shared__ float sm[13056];
  float* m_q  = sm;
  float* part = sm + 8448;
  float* p_s  = sm + 12544;

  const int t     = threadIdx.x;
  const int r     = blockIdx.x;
  const int j     = t & 63;
  const int cseg  = t >> 6;
  const int csegu = __builtin_amdgcn_readfirstlane(cseg);

  // ---- stage this thread's 64-float slice of the mems row block into regs
  const float4* mrow =
      (const float4*)(mems + ((size_t)r * 64 + j) * 512 + cseg * 64);
  float4 mr[16];
#pragma unroll
  for (int i = 0; i < 16; ++i) mr[i] = mrow[i];

  // ---- sim partials over this thread's c-slice (T via scalar loads)
  const float* Trow = Tm + (size_t)r * 4096 + csegu * 64;
  float acc[8];
#pragma unroll
  for (int h = 0; h < 8; ++h) acc[h] = 0.f;
#pragma unroll
  for (int i = 0; i < 16; ++i) {
    float4 mv = mr[i];
#pragma unroll
    for (int h = 0; h < 8; ++h) {
      float4 tv = *(const float4*)(Trow + h * 512 + i * 4);  // uniform -> s_load
      acc[h] += mv.x * tv.x + mv.y * tv.y + mv.z * tv.z + mv.w * tv.w;
    }
  }
#pragma unroll
  for (int h = 0; h < 8; ++h) part[cseg * 512 + h * 64 + j] = acc[h];
  __syncthreads();

  // ---- reduce 8 c-segment partials; mask; per-head softmax (wave h, lane j)
  {
    const int h = cseg;
    float s = 0.f;
#pragma unroll
    for (int cs = 0; cs < 8; ++cs) s += part[cs * 512 + h * 64 + j];
    const bool mk = mask[(size_t)r * 64 + j] != 0;
    s = mk ? s : -FLT_MAX;                       // matches jnp.where mask_value
    float mx = s;
#pragma unroll
    for (int o = 32; o > 0; o >>= 1) mx = fmaxf(mx, __shfl_xor(mx, o));
    float ev = mk ? __expf(s - mx) : 0.f;
    float l = ev;
#pragma unroll
    for (int o = 32; o > 0; o >>= 1) l += __shfl_xor(l, o);
    p_s[j * 8 + h] = ev / l;                     // normalized attention weight
  }
  __syncthreads();

  // ---- cbar[h][c] = sum_j p[h][j] * m[j][c], in 4 phases of 128 columns
  const int cc = t & 127;
  const int jh = t >> 7;   // j-group 0..3 (16 j's each)
  for (int q = 0; q < 4; ++q) {
    if ((cseg >> 1) == q) {                      // this thread's slice is in phase q
      float* dst = m_q + j * 132 + (cseg & 1) * 64;
#pragma unroll
      for (int i = 0; i < 16; ++i) *(float4*)(dst + i * 4) = mr[i];
    }
    __syncthreads();                             // m_q ready
    float cb[8];
#pragma unroll
    for (int h = 0; h < 8; ++h) cb[h] = 0.f;
#pragma unroll
    for (int k = 0; k < 16; ++k) {
      const int jj = jh * 16 + k;
      float  mv = m_q[jj * 132 + cc];            // lanes consecutive-c: conflict-free
      float4 pa = *(const float4*)(p_s + jj * 8);      // wave-uniform broadcast
      float4 pb = *(const float4*)(p_s + jj * 8 + 4);
      cb[0] += pa.x * mv; cb[1] += pa.y * mv; cb[2] += pa.z * mv; cb[3] += pa.w * mv;
      cb[4] += pb.x * mv; cb[5] += pb.y * mv; cb[6] += pb.z * mv; cb[7] += pb.w * mv;
    }
#pragma unroll
    for (int h = 0; h < 8; ++h) part[(jh * 8 + h) * 128 + cc] = cb[h];
    __syncthreads();                             // partials ready
#pragma unroll
    for (int w = 0; w < 2; ++w) {
      const int idx = t + w * 512;
      const int h  = idx >> 7;
      const int c2 = idx & 127;
      float v = part[(0 * 8 + h) * 128 + c2] + part[(1 * 8 + h) * 128 + c2] +
                part[(2 * 8 + h) * 128 + c2] + part[(3 * 8 + h) * 128 + c2];
      cbar[(size_t)r * 4096 + h * 512 + q * 128 + c2] = v;
    }
    __syncthreads();                             // before next phase reuses LDS
  }
}

// ---------------------------------------------------------------------------
extern "C" void kernel_launch(void* const* d_in, const int* in_sizes, int n_in,
                              void* d_out, int out_size, void* d_ws, size_t ws_size,
                              hipStream_t stream)
{
  const float* x    = (const float*)d_in[0];   // [2048][512]
  const float* mems = (const float*)d_in[1];   // [2048][64][512]
  const int*   mask = (const int*)  d_in[2];   // [2048][64]
  const float* Wq   = (const float*)d_in[3];   // [512][512]
  const float* Wkv  = (const float*)d_in[4];   // [512][1024] (k | v)
  const float* Wo   = (const float*)d_in[5];   // [512][512]
  const float* bo   = (const float*)d_in[6];   // [512]
  float* out = (float*)d_out;                  // [2048][512]

  float* Q  = (float*)d_ws;                    // 2048*512
  float* Tm = Q  + (size_t)2048 * 512;         // 2048*4096
  float* cb = Tm + (size_t)2048 * 4096;        // 2048*4096
  float* O  = cb + (size_t)2048 * 4096;        // 2048*512   (72 MB total)

  // Q = SCALE * X @ Wq
  k_clrb<<<256, 512, 0, stream>>>(x, 512, 0, Wq, 512, 0, nullptr, SCALE, Q, 512, 512);
  // T[r][h][e] = sum_d Q[r][h*64+d] * Wkv[e][h*64+d]
  k_tmat<<<dim3(256, 8), 512, 0, stream>>>(Q, Wkv, Tm);
  // fused sim -> mask -> softmax -> cbar (single pass over mems)
  k_attn<<<2048, 512, 0, stream>>>(mems, Tm, mask, cb);
  // O[r][h*64+d] = sum_e cbar[r][h*512+e] * Wkv[e][512 + h*64+d]
  k_clrb<<<256, 512, 0, stream>>>(cb, 4096, 512, Wkv, 1024, 512, nullptr, 1.f, O, 512, 512);
  // out = O @ Wo + bo
  k_clrb<<<256, 512, 0, stream>>>(O, 512, 0, Wo, 512, 0, bo, 1.f, out, 512, 512);
}